// Round 1
// baseline (211.149 us; speedup 1.0000x reference)
//
#include <hip/hip_runtime.h>
#include <math.h>

#define NSTATES 21
#define NPULSES 128
#define BATCH   8192

// Lane layout: 3 batch elements per wave (21 lanes each), lane 63 idle.
// Thread (b, s) holds Fpf (complex), Fmf (complex), Zf, Zb for state s.
// EPG shift = +/-1 lane shuffle with s==0 / s==20 zero-fill (which also
// masks cross-group leakage, since groups start at s==0).
__global__ __launch_bounds__(256) void epg_mt_kernel(
    const float* __restrict__ fa_arr,
    const float* __restrict__ ph_arr,
    const float* __restrict__ T1f, const float* __restrict__ T2f,
    const float* __restrict__ T1b, const float* __restrict__ T2b,
    const float* __restrict__ kfp, const float* __restrict__ kbp,
    const float* __restrict__ B0p, const float* __restrict__ B1p,
    const float* __restrict__ wfp, const float* __restrict__ wbp,
    const int*   __restrict__ TRp,
    float* __restrict__ out)
{
    const int lane = threadIdx.x & 63;
    const int wid  = (int)((blockIdx.x * blockDim.x + threadIdx.x) >> 6);
    const int g    = lane / 21;          // 0..2 valid, 3 == idle lane 63
    const int s    = lane - g * 21;      // state index 0..20
    const int b    = wid * 3 + g;
    if (g >= 3 || b >= BATCH) return;

    const float tr  = (float)TRp[0];
    const float dt  = tr * 0.001f;
    const float E1f = expf(-tr / T1f[b]);
    const float E2f = expf(-tr / T2f[b]);
    const float E1b = expf(-tr / T1b[b]);
    // E2b unused: bound-pool F states are identically zero (never excited).
    const float kfdt = kfp[b] * dt;
    const float kbdt = kbp[b] * dt;
    const float phi  = 6.28318530717958647692f * B0p[b] * dt;
    const float b0c  = cosf(phi), b0s = sinf(phi);
    const float wfv  = wfp[b], wbv = wbp[b];
    const float add0f = (s == 0) ? (1.0f - E1f) * wfv : 0.0f;  // T1 recovery, state 0 only
    const float add0b = (s == 0) ? (1.0f - E1b) * wbv : 0.0f;
    const float b1   = B1p[b];

    float Fpr = 0.f, Fpi = 0.f, Fmr = 0.f, Fmi = 0.f;
    float Zf = (s == 0) ? wfv : 0.f;
    float Zb = (s == 0) ? wbv : 0.f;

    float* op = out + (size_t)b * (NSTATES * 10) + (size_t)s * 10;
    const size_t pstride = (size_t)BATCH * NSTATES * 10;

    for (int p = 0; p < NPULSES; ++p) {
        const float fa = fa_arr[p];
        const float ph = ph_arr[p];

        // --- relax + exchange ---
        Fpr *= E2f; Fpi *= E2f; Fmr *= E2f; Fmi *= E2f;
        const float dZf = kbdt * Zb - kfdt * Zf;
        const float dZb = kfdt * Zf - kbdt * Zb;
        const float nZf1 = fmaf(Zf, E1f, add0f) + dZf;
        const float nZb1 = fmaf(Zb, E1b, add0b) + dZb;
        Zf = nZf1; Zb = nZb1;

        // --- B0 precession (free pool; bound F is zero) ---
        {
            const float r  = Fpr * b0c - Fpi * b0s;
            const float i_ = Fpr * b0s + Fpi * b0c;
            const float r2 = Fmr * b0c + Fmi * b0s;
            const float i2 = Fmi * b0c - Fmr * b0s;
            Fpr = r; Fpi = i_; Fmr = r2; Fmi = i2;
        }

        // --- RF pulse (free pool only) ---
        const float half = 0.5f * fa * b1;
        const float ca = __cosf(half), sa = __sinf(half);
        const float cph = __cosf(ph), sph = __sinf(ph);
        const float ca2 = ca * ca, sa2 = sa * sa, casa = ca * sa;
        const float cd  = ca2 - sa2;
        const float e2c = cph * cph - sph * sph;     // Re(eib^2)
        const float e2s = 2.f * cph * sph;           // Im(eib^2)
        // conj(Fmf) * eib^2
        const float t1r = Fmr * e2c + Fmi * e2s;
        const float t1i = Fmr * e2s - Fmi * e2c;
        // conj(Fpf) * conj(eib^2)
        const float t2r = Fpr * e2c - Fpi * e2s;
        const float t2i = -(Fpr * e2s) - Fpi * e2c;
        const float zc = Zf * cph, zs = Zf * sph;    // Zf * eib
        const float nFpr = ca2 * Fpr + sa2 * t1r - casa * zs;
        const float nFpi = ca2 * Fpi + sa2 * t1i + casa * zc;
        const float nFmr = sa2 * t2r + ca2 * Fmr - casa * zs;
        const float nFmi = sa2 * t2i + ca2 * Fmi - casa * zc;
        // Zf' = ca*sa*Im[Fpf*emib - Fmf*eib] + (ca^2 - sa^2)*Zf
        const float nZf = casa * ((Fpi * cph - Fpr * sph) - (Fmi * cph + Fmr * sph)) + cd * Zf;
        Fpr = nFpr; Fpi = nFpi; Fmr = nFmr; Fmi = nFmi; Zf = nZf;

        // --- EPG shift ---
        const float sFpr = __shfl_up(Fpr, 1);
        const float sFpi = __shfl_up(Fpi, 1);
        const float sZf  = __shfl_up(Zf, 1);
        const float sZb  = __shfl_up(Zb, 1);
        const float sFmr = __shfl_down(Fmr, 1);
        const float sFmi = __shfl_down(Fmi, 1);
        const bool s0 = (s == 0), sE = (s == NSTATES - 1);
        Fpr = s0 ? 0.f : sFpr;
        Fpi = s0 ? 0.f : sFpi;
        Zf  = s0 ? 0.f : sZf;
        Zb  = s0 ? 0.f : sZb;
        Fmr = sE ? 0.f : sFmr;
        Fmi = sE ? 0.f : sFmi;

        // --- store packed state (10 floats, 8B-aligned -> 5x float2) ---
        float2* o2 = (float2*)op;
        o2[0] = make_float2(Fpr, Fpi);
        o2[1] = make_float2(Fmr, Fmi);
        o2[2] = make_float2(Zf, 0.f);
        o2[3] = make_float2(0.f, 0.f);   // bound-pool F states: always zero
        o2[4] = make_float2(0.f, Zb);
        op += pstride;
    }
}

extern "C" void kernel_launch(void* const* d_in, const int* in_sizes, int n_in,
                              void* d_out, int out_size, void* d_ws, size_t ws_size,
                              hipStream_t stream) {
    const float* fa  = (const float*)d_in[0];
    const float* ph  = (const float*)d_in[1];
    const float* T1f = (const float*)d_in[2];
    const float* T2f = (const float*)d_in[3];
    const float* T1b = (const float*)d_in[4];
    const float* T2b = (const float*)d_in[5];
    const float* kf  = (const float*)d_in[6];
    const float* kb  = (const float*)d_in[7];
    const float* B0  = (const float*)d_in[8];
    const float* B1  = (const float*)d_in[9];
    const float* wf  = (const float*)d_in[10];
    const float* wb  = (const float*)d_in[11];
    const int*   TR  = (const int*)d_in[12];
    float* out = (float*)d_out;

    const int waves  = (BATCH + 2) / 3;          // 2731 waves (3 batch elems each)
    const int blocks = (waves + 3) / 4;          // 4 waves (256 thr) per block
    epg_mt_kernel<<<blocks, 256, 0, stream>>>(fa, ph, T1f, T2f, T1b, T2b,
                                              kf, kb, B0, B1, wf, wb, TR, out);
}

// Round 2
// 205.941 us; speedup vs baseline: 1.0253x; 1.0253x over previous
//
#include <hip/hip_runtime.h>
#include <math.h>

#define NSTATES 21
#define NPULSES 128
#define BATCH   8192
#define BPB     12   // batch elems per block: 4 waves x 3 per wave

// Lane layout: 3 batch elements per wave (21 lanes each), lane 63 idle.
// Thread (b, s) holds Fpf (complex), Fmf (complex), Zf, Zb for state s.
// EPG shift = +/-1 lane shuffle with s==0 / s==20 zero-fill.
// Output staged through LDS so global stores are contiguous dwordx4:
// block's 12 batch elems form a contiguous 10080 B (16B-aligned) region/pulse.
__global__ __launch_bounds__(256) void epg_mt_kernel(
    const float* __restrict__ fa_arr,
    const float* __restrict__ ph_arr,
    const float* __restrict__ T1f, const float* __restrict__ T2f,
    const float* __restrict__ T1b, const float* __restrict__ T2b,
    const float* __restrict__ kfp, const float* __restrict__ kbp,
    const float* __restrict__ B0p, const float* __restrict__ B1p,
    const float* __restrict__ wfp, const float* __restrict__ wbp,
    const int*   __restrict__ TRp,
    float* __restrict__ out)
{
    __shared__ float lds[2][BPB * NSTATES * 10];   // 2 x 2520 floats = 20160 B

    const int tid  = threadIdx.x;
    const int lane = tid & 63;
    const int g    = lane / 21;               // 0..2 valid, 3 == idle lane 63
    const int s    = lane - g * 21;           // state 0..20
    const int lb   = (tid >> 6) * 3 + g;      // local batch index 0..11
    const int b0   = blockIdx.x * BPB;
    const int b    = b0 + lb;
    const bool valid = (g < 3) && (b < BATCH);
    const int bc   = valid ? b : 0;           // clamped for safe param loads

    // Zero both LDS buffers once: the always-zero fields (bound-pool F
    // states) are never rewritten, so they stay zero for every pulse.
    for (int i = tid; i < 2 * BPB * NSTATES * 10; i += 256)
        ((float*)lds)[i] = 0.f;

    const float tr  = (float)TRp[0];
    const float dt  = tr * 0.001f;
    const float E1f = expf(-tr / T1f[bc]);
    const float E2f = expf(-tr / T2f[bc]);
    const float E1b = expf(-tr / T1b[bc]);
    const float kfdt = kfp[bc] * dt;
    const float kbdt = kbp[bc] * dt;
    const float phi  = 6.28318530717958647692f * B0p[bc] * dt;
    const float b0c  = cosf(phi), b0s = sinf(phi);
    const float wfv  = wfp[bc], wbv = wbp[bc];
    const float add0f = (s == 0) ? (1.0f - E1f) * wfv : 0.0f;
    const float add0b = (s == 0) ? (1.0f - E1b) * wbv : 0.0f;
    const float b1   = B1p[bc];

    float Fpr = 0.f, Fpi = 0.f, Fmr = 0.f, Fmi = 0.f;
    float Zf = (s == 0) ? wfv : 0.f;
    float Zb = (s == 0) ? wbv : 0.f;

    const int nb = (BATCH - b0 < BPB) ? (BATCH - b0) : BPB;
    const int n4 = (nb * NSTATES * 10) >> 2;             // float4s per pulse
    const size_t pstride = (size_t)BATCH * NSTATES * 10; // floats per pulse
    float* outb = out + (size_t)b0 * (NSTATES * 10);

    __syncthreads();   // LDS zero-init visible

    for (int p = 0; p < NPULSES; ++p) {
        const float fa = fa_arr[p];
        const float ph = ph_arr[p];

        // --- relax + exchange ---
        Fpr *= E2f; Fpi *= E2f; Fmr *= E2f; Fmi *= E2f;
        const float dZf = kbdt * Zb - kfdt * Zf;
        const float dZb = kfdt * Zf - kbdt * Zb;
        const float nZf1 = fmaf(Zf, E1f, add0f) + dZf;
        const float nZb1 = fmaf(Zb, E1b, add0b) + dZb;
        Zf = nZf1; Zb = nZb1;

        // --- B0 precession (free pool; bound F is zero) ---
        {
            const float r  = Fpr * b0c - Fpi * b0s;
            const float i_ = Fpr * b0s + Fpi * b0c;
            const float r2 = Fmr * b0c + Fmi * b0s;
            const float i2 = Fmi * b0c - Fmr * b0s;
            Fpr = r; Fpi = i_; Fmr = r2; Fmi = i2;
        }

        // --- RF pulse (free pool only) ---
        const float half = 0.5f * fa * b1;
        const float ca = __cosf(half), sa = __sinf(half);
        const float cph = __cosf(ph), sph = __sinf(ph);
        const float ca2 = ca * ca, sa2 = sa * sa, casa = ca * sa;
        const float cd  = ca2 - sa2;
        const float e2c = cph * cph - sph * sph;     // Re(eib^2)
        const float e2s = 2.f * cph * sph;           // Im(eib^2)
        const float t1r = Fmr * e2c + Fmi * e2s;     // conj(Fmf)*eib^2
        const float t1i = Fmr * e2s - Fmi * e2c;
        const float t2r = Fpr * e2c - Fpi * e2s;     // conj(Fpf)*conj(eib^2)
        const float t2i = -(Fpr * e2s) - Fpi * e2c;
        const float zc = Zf * cph, zs = Zf * sph;    // Zf * eib
        const float nFpr = ca2 * Fpr + sa2 * t1r - casa * zs;
        const float nFpi = ca2 * Fpi + sa2 * t1i + casa * zc;
        const float nFmr = sa2 * t2r + ca2 * Fmr - casa * zs;
        const float nFmi = sa2 * t2i + ca2 * Fmi - casa * zc;
        const float nZf = casa * ((Fpi * cph - Fpr * sph) - (Fmi * cph + Fmr * sph)) + cd * Zf;
        Fpr = nFpr; Fpi = nFpi; Fmr = nFmr; Fmi = nFmi; Zf = nZf;

        // --- EPG shift (lane +/-1 shuffles; boundaries zero-filled) ---
        const float sFpr = __shfl_up(Fpr, 1);
        const float sFpi = __shfl_up(Fpi, 1);
        const float sZf  = __shfl_up(Zf, 1);
        const float sZb  = __shfl_up(Zb, 1);
        const float sFmr = __shfl_down(Fmr, 1);
        const float sFmi = __shfl_down(Fmi, 1);
        const bool s0 = (s == 0), sE = (s == NSTATES - 1);
        Fpr = s0 ? 0.f : sFpr;
        Fpi = s0 ? 0.f : sFpi;
        Zf  = s0 ? 0.f : sZf;
        Zb  = s0 ? 0.f : sZb;
        Fmr = sE ? 0.f : sFmr;
        Fmi = sE ? 0.f : sFmi;

        // --- stage nonzero fields into LDS (zero fields persist) ---
        float* Lb = lds[p & 1];
        if (valid) {
            float* dst = Lb + lb * (NSTATES * 10) + s * 10;
            ((float2*)dst)[0] = make_float2(Fpr, Fpi);
            ((float2*)dst)[1] = make_float2(Fmr, Fmi);
            dst[4] = Zf;
            dst[9] = Zb;
        }
        __syncthreads();

        // --- block-cooperative coalesced dwordx4 store ---
        const float4* Ls = (const float4*)(lds[p & 1]);
        float4* og = (float4*)(outb + (size_t)p * pstride);
        for (int i = tid; i < n4; i += 256)
            og[i] = Ls[i];
        // No second barrier: double-buffered LDS; pulse p+2 reuses this
        // buffer only after the barrier at pulse p+1, by which point this
        // wave's reads (lgkmcnt-flushed at that barrier) are complete.
    }
}

extern "C" void kernel_launch(void* const* d_in, const int* in_sizes, int n_in,
                              void* d_out, int out_size, void* d_ws, size_t ws_size,
                              hipStream_t stream) {
    const float* fa  = (const float*)d_in[0];
    const float* ph  = (const float*)d_in[1];
    const float* T1f = (const float*)d_in[2];
    const float* T2f = (const float*)d_in[3];
    const float* T1b = (const float*)d_in[4];
    const float* T2b = (const float*)d_in[5];
    const float* kf  = (const float*)d_in[6];
    const float* kb  = (const float*)d_in[7];
    const float* B0  = (const float*)d_in[8];
    const float* B1  = (const float*)d_in[9];
    const float* wf  = (const float*)d_in[10];
    const float* wb  = (const float*)d_in[11];
    const int*   TR  = (const int*)d_in[12];
    float* out = (float*)d_out;

    const int blocks = (BATCH + BPB - 1) / BPB;   // 683
    epg_mt_kernel<<<blocks, 256, 0, stream>>>(fa, ph, T1f, T2f, T1b, T2b,
                                              kf, kb, B0, B1, wf, wb, TR, out);
}